// Round 14
// baseline (13996.220 us; speedup 1.0000x reference)
//
#include <hip/hip_runtime.h>
#include <math.h>

#define TT 128

typedef __attribute__((ext_vector_type(8))) short s8v;
typedef __attribute__((ext_vector_type(4))) float f4v;

__device__ __forceinline__ unsigned short f2bf(float f) {
  union { float f; unsigned int u; } v; v.f = f;
  unsigned int u = v.u;
  u += 0x7FFFu + ((u >> 16) & 1u);
  return (unsigned short)(u >> 16);
}
__device__ __forceinline__ float bf2f(unsigned short h) {
  union { unsigned int u; float f; } v; v.u = ((unsigned int)h) << 16;
  return v.f;
}
__device__ __forceinline__ void split3(float x, unsigned short& h, unsigned short& m, unsigned short& l) {
  h = f2bf(x);
  float r1 = x - bf2f(h);
  m = f2bf(r1);
  l = f2bf(r1 - bf2f(m));
}
__device__ __forceinline__ void gload16(const void* g, void* l) {
  __builtin_amdgcn_global_load_lds(
      (const __attribute__((address_space(1))) void*)g,
      (__attribute__((address_space(3))) void*)l, 16, 0, 0);
}

struct GP {
  const unsigned short *Ah, *Am, *Al;    // A planes [rows,1024]
  const unsigned short *A2h, *A2m, *A2l; // MODE1: tanh(mem) planes
  const float* Ax;          // x-proj: x_t fp32
  long long strideAx;
  const unsigned short *Bh, *Bm, *Bl;    // weight planes [Nrows,1024]
  const unsigned short *Ch, *Cm, *Cl;    // MODE4: cat planes for fused x-proj
  const float* bias;
  const float* xbias;
  float* o0;                // qkvg (MODE1) / naF (MODE2)
  float* xkv;               // x-proj OUTPUT buffer [64,4096]
  const float* rf; const float* g1; const float* g2;
  float* memf;
  unsigned short *oh, *om, *ol;
  unsigned short *o2h, *o2m, *o2l;
};

// x-projection block: x_row(t) @ cat[Wk|Wv|Ww] + xbias -> xkv [64,4096], 64x64 tile per bn.
// Identical arithmetic/order to r11's MODE1 xr path (bit-identical output).
__device__ __forceinline__ void xproj_block(
    int bn, int tid, const float* Ax, long long strideAx,
    const unsigned short* Bh, const unsigned short* Bm, const unsigned short* Bl,
    const float* xbias, float* xkv,
    unsigned short* lAh, unsigned short* lAm, unsigned short* lAl,
    unsigned short* lBh, unsigned short* lBm, unsigned short* lBl) {
  const int lane = tid & 63;
  const int wave = tid >> 6;
  const int wm = (wave >> 1) << 5;
  const int wn = (wave & 1) << 5;
  const int wrow0 = (bn < 32) ? (1024 + (bn << 6)) : (5120 + ((bn - 32) << 6));
  const int lr = lane >> 3, lc = lane & 7;

  f4v acc[2][2];
#pragma unroll
  for (int i = 0; i < 2; ++i)
#pragma unroll
    for (int j = 0; j < 2; ++j)
#pragma unroll
      for (int r = 0; r < 4; ++r) acc[i][j][r] = 0.f;

  for (int kt = 0; kt < 16; ++kt) {
    const int kcol = kt << 6;
#pragma unroll
    for (int h = 0; h < 2; ++h) {
      const int r = (tid >> 3) + (h << 5);
      const int sc = tid & 7;
      const float4* fp = reinterpret_cast<const float4*>(Ax + (size_t)r * strideAx + kcol + (sc << 3));
      float4 f0 = fp[0], f1 = fp[1];
      float fv[8] = { f0.x, f0.y, f0.z, f0.w, f1.x, f1.y, f1.z, f1.w };
      s8v ah, am, al;
#pragma unroll
      for (int e = 0; e < 8; ++e) {
        unsigned short hb, mb, lb;
        split3(fv[e], hb, mb, lb);
        ah[e] = (short)hb; am[e] = (short)mb; al[e] = (short)lb;
      }
      const int pos = (r << 6) + ((sc ^ (r & 7)) << 3);
      *reinterpret_cast<s8v*>(&lAh[pos]) = ah;
      *reinterpret_cast<s8v*>(&lAm[pos]) = am;
      *reinterpret_cast<s8v*>(&lAl[pos]) = al;
    }
#pragma unroll
    for (int rep = 0; rep < 2; ++rep) {
      const int rbase = (wave << 3) + (rep << 5);
      const int r = rbase + lr;
      const size_t so = (size_t)(wrow0 + r) * 1024 + kcol + ((lc ^ (r & 7)) << 3);
      gload16(Bh + so, &lBh[rbase << 6]);
      gload16(Bm + so, &lBm[rbase << 6]);
      gload16(Bl + so, &lBl[rbase << 6]);
    }
    __syncthreads();
#pragma unroll
    for (int ks = 0; ks < 2; ++ks) {
      s8v afh[2], afm[2], afl[2], bfh[2], bfm[2], bfl[2];
#pragma unroll
      for (int i = 0; i < 2; ++i) {
        const int rr = wm + (i << 4) + (lane & 15);
        const int cc = (ks << 2) + (lane >> 4);
        const int pos = (rr << 6) + ((cc ^ (rr & 7)) << 3);
        afh[i] = *reinterpret_cast<const s8v*>(&lAh[pos]);
        afm[i] = *reinterpret_cast<const s8v*>(&lAm[pos]);
        afl[i] = *reinterpret_cast<const s8v*>(&lAl[pos]);
      }
#pragma unroll
      for (int j = 0; j < 2; ++j) {
        const int rr = wn + (j << 4) + (lane & 15);
        const int cc = (ks << 2) + (lane >> 4);
        const int pos = (rr << 6) + ((cc ^ (rr & 7)) << 3);
        bfh[j] = *reinterpret_cast<const s8v*>(&lBh[pos]);
        bfm[j] = *reinterpret_cast<const s8v*>(&lBm[pos]);
        bfl[j] = *reinterpret_cast<const s8v*>(&lBl[pos]);
      }
#pragma unroll
      for (int i = 0; i < 2; ++i)
#pragma unroll
        for (int j = 0; j < 2; ++j) {
          acc[i][j] = __builtin_amdgcn_mfma_f32_16x16x32_bf16(afl[i], bfh[j], acc[i][j], 0, 0, 0);
          acc[i][j] = __builtin_amdgcn_mfma_f32_16x16x32_bf16(afh[i], bfl[j], acc[i][j], 0, 0, 0);
          acc[i][j] = __builtin_amdgcn_mfma_f32_16x16x32_bf16(afm[i], bfm[j], acc[i][j], 0, 0, 0);
          acc[i][j] = __builtin_amdgcn_mfma_f32_16x16x32_bf16(afm[i], bfh[j], acc[i][j], 0, 0, 0);
          acc[i][j] = __builtin_amdgcn_mfma_f32_16x16x32_bf16(afh[i], bfm[j], acc[i][j], 0, 0, 0);
          acc[i][j] = __builtin_amdgcn_mfma_f32_16x16x32_bf16(afh[i], bfh[j], acc[i][j], 0, 0, 0);
        }
    }
    __syncthreads();
  }

#pragma unroll
  for (int i = 0; i < 2; ++i)
#pragma unroll
    for (int j = 0; j < 2; ++j) {
      const int lcol = wn + (j << 4) + (lane & 15);
#pragma unroll
      for (int rg = 0; rg < 4; ++rg) {
        const int grow = wm + (i << 4) + ((lane >> 4) << 2) + rg;
        const int gcol = (bn < 32) ? ((bn << 6) + lcol) : (2048 + ((bn - 32) << 6) + lcol);
        xkv[(size_t)grow * 4096 + gcol] = acc[i][j][rg] + xbias[gcol];
      }
    }
}

// MODE 1: QKV|g2 (64x64, BK=64, flat 640, XCD-chunked; x-proj removed)
// MODE 2/3: 32x32, BK=128, flat 512. MODE 4: same + blocks 512..575 run x-proj for t+1.
// MODE 5: standalone 64-block x-proj prologue (t=0).
template<int MODE>
__global__ __launch_bounds__(256) void gemm_k(GP p) {
  __shared__ __align__(16) unsigned short lAh[4096];
  __shared__ __align__(16) unsigned short lAm[4096];
  __shared__ __align__(16) unsigned short lAl[4096];
  __shared__ __align__(16) unsigned short lBh[4096];
  __shared__ __align__(16) unsigned short lBm[4096];
  __shared__ __align__(16) unsigned short lBl[4096];
  const int tid = threadIdx.x;

  if (MODE == 5) {
    xproj_block(blockIdx.x, tid, p.Ax, p.strideAx, p.Bh, p.Bm, p.Bl, p.xbias, p.xkv,
                lAh, lAm, lAl, lBh, lBm, lBl);
    return;
  }
  if (MODE == 4 && blockIdx.x >= 512) {
    xproj_block(blockIdx.x - 512, tid, p.Ax, p.strideAx, p.Ch, p.Cm, p.Cl, p.xbias, p.xkv,
                lAh, lAm, lAl, lBh, lBm, lBl);
    return;
  }

  constexpr int BM = (MODE == 1) ? 64 : 32;
  constexpr int BN = (MODE == 1) ? 64 : 32;
  constexpr int MI = BM / 32;
  constexpr int NJ = BN / 32;

  int bn, bm;
  if (MODE == 1) {
    const int fid = blockIdx.x;                  // 0..639
    const int wid = (fid & 7) * 80 + (fid >> 3); // XCD k: wid in [80k, 80k+80)
    bn = wid >> 3; bm = wid & 7;                 // per XCD: 10 bn x 8 bm
  } else {
    const int fid = blockIdx.x;                  // 0..511
    const int wid = (fid & 7) * 64 + (fid >> 3);
    bn = wid >> 4; bm = wid & 15;
  }

  const int lane = tid & 63;
  const int wave = tid >> 6;
  const int wm = (wave >> 1) * (BM / 2);
  const int wn = (wave & 1) * (BN / 2);
  const int rowA0 = bm * BM;
  const int wrow0 = bn * BN;

  const unsigned short* Ah = p.Ah;
  const unsigned short* Am = p.Am;
  const unsigned short* Al = p.Al;
  if (MODE == 1 && bn >= 48) { Ah = p.A2h; Am = p.A2m; Al = p.A2l; }

  f4v acc[MI][NJ];
#pragma unroll
  for (int i = 0; i < MI; ++i)
#pragma unroll
    for (int j = 0; j < NJ; ++j)
#pragma unroll
      for (int r = 0; r < 4; ++r) acc[i][j][r] = 0.f;

  if (MODE == 1) {
    const int lr = lane >> 3, lc = lane & 7;
    for (int kt = 0; kt < 16; ++kt) {
      const int kcol = kt << 6;
#pragma unroll
      for (int rep = 0; rep < MI; ++rep) {
        const int rbase = (wave << 3) + (rep << 5);
        const int r = rbase + lr;
        const size_t so = (size_t)(rowA0 + r) * 1024 + kcol + ((lc ^ (r & 7)) << 3);
        gload16(Ah + so, &lAh[rbase << 6]);
        gload16(Am + so, &lAm[rbase << 6]);
        gload16(Al + so, &lAl[rbase << 6]);
      }
#pragma unroll
      for (int rep = 0; rep < NJ; ++rep) {
        const int rbase = (wave << 3) + (rep << 5);
        const int r = rbase + lr;
        const size_t so = (size_t)(wrow0 + r) * 1024 + kcol + ((lc ^ (r & 7)) << 3);
        gload16(p.Bh + so, &lBh[rbase << 6]);
        gload16(p.Bm + so, &lBm[rbase << 6]);
        gload16(p.Bl + so, &lBl[rbase << 6]);
      }
      __syncthreads();
#pragma unroll
      for (int ks = 0; ks < 2; ++ks) {
        s8v afh[MI], afm[MI], afl[MI], bfh[NJ], bfm[NJ], bfl[NJ];
#pragma unroll
        for (int i = 0; i < MI; ++i) {
          const int rr = wm + (i << 4) + (lane & 15);
          const int cc = (ks << 2) + (lane >> 4);
          const int pos = (rr << 6) + ((cc ^ (rr & 7)) << 3);
          afh[i] = *reinterpret_cast<const s8v*>(&lAh[pos]);
          afm[i] = *reinterpret_cast<const s8v*>(&lAm[pos]);
          afl[i] = *reinterpret_cast<const s8v*>(&lAl[pos]);
        }
#pragma unroll
        for (int j = 0; j < NJ; ++j) {
          const int rr = wn + (j << 4) + (lane & 15);
          const int cc = (ks << 2) + (lane >> 4);
          const int pos = (rr << 6) + ((cc ^ (rr & 7)) << 3);
          bfh[j] = *reinterpret_cast<const s8v*>(&lBh[pos]);
          bfm[j] = *reinterpret_cast<const s8v*>(&lBm[pos]);
          bfl[j] = *reinterpret_cast<const s8v*>(&lBl[pos]);
        }
#pragma unroll
        for (int i = 0; i < MI; ++i)
#pragma unroll
          for (int j = 0; j < NJ; ++j) {
            acc[i][j] = __builtin_amdgcn_mfma_f32_16x16x32_bf16(afl[i], bfh[j], acc[i][j], 0, 0, 0);
            acc[i][j] = __builtin_amdgcn_mfma_f32_16x16x32_bf16(afh[i], bfl[j], acc[i][j], 0, 0, 0);
            acc[i][j] = __builtin_amdgcn_mfma_f32_16x16x32_bf16(afm[i], bfm[j], acc[i][j], 0, 0, 0);
            acc[i][j] = __builtin_amdgcn_mfma_f32_16x16x32_bf16(afm[i], bfh[j], acc[i][j], 0, 0, 0);
            acc[i][j] = __builtin_amdgcn_mfma_f32_16x16x32_bf16(afh[i], bfm[j], acc[i][j], 0, 0, 0);
            acc[i][j] = __builtin_amdgcn_mfma_f32_16x16x32_bf16(afh[i], bfh[j], acc[i][j], 0, 0, 0);
          }
      }
      __syncthreads();
    }
  } else {
    for (int kt = 0; kt < 8; ++kt) {
      const int kcol = kt << 7;
#pragma unroll
      for (int rep = 0; rep < 2; ++rep) {
        const int rbase = (wave << 2) + (rep << 4);
        const int r = rbase + (lane >> 4);
        const int c = lane & 15;
        const size_t soA = (size_t)(rowA0 + r) * 1024 + kcol + ((c ^ (r & 7)) << 3);
        gload16(Ah + soA, &lAh[rbase << 7]);
        gload16(Am + soA, &lAm[rbase << 7]);
        gload16(Al + soA, &lAl[rbase << 7]);
        const size_t soB = (size_t)(wrow0 + r) * 1024 + kcol + ((c ^ (r & 7)) << 3);
        gload16(p.Bh + soB, &lBh[rbase << 7]);
        gload16(p.Bm + soB, &lBm[rbase << 7]);
        gload16(p.Bl + soB, &lBl[rbase << 7]);
      }
      __syncthreads();
#pragma unroll
      for (int ks = 0; ks < 4; ++ks) {
        s8v afh, afm, afl, bfh, bfm, bfl;
        {
          const int rr = wm + (lane & 15);
          const int cc = (ks << 2) + (lane >> 4);
          const int pos = (rr << 7) + ((cc ^ (rr & 7)) << 3);
          afh = *reinterpret_cast<const s8v*>(&lAh[pos]);
          afm = *reinterpret_cast<const s8v*>(&lAm[pos]);
          afl = *reinterpret_cast<const s8v*>(&lAl[pos]);
        }
        {
          const int rr = wn + (lane & 15);
          const int cc = (ks << 2) + (lane >> 4);
          const int pos = (rr << 7) + ((cc ^ (rr & 7)) << 3);
          bfh = *reinterpret_cast<const s8v*>(&lBh[pos]);
          bfm = *reinterpret_cast<const s8v*>(&lBm[pos]);
          bfl = *reinterpret_cast<const s8v*>(&lBl[pos]);
        }
        acc[0][0] = __builtin_amdgcn_mfma_f32_16x16x32_bf16(afl, bfh, acc[0][0], 0, 0, 0);
        acc[0][0] = __builtin_amdgcn_mfma_f32_16x16x32_bf16(afh, bfl, acc[0][0], 0, 0, 0);
        acc[0][0] = __builtin_amdgcn_mfma_f32_16x16x32_bf16(afm, bfm, acc[0][0], 0, 0, 0);
        acc[0][0] = __builtin_amdgcn_mfma_f32_16x16x32_bf16(afm, bfh, acc[0][0], 0, 0, 0);
        acc[0][0] = __builtin_amdgcn_mfma_f32_16x16x32_bf16(afh, bfm, acc[0][0], 0, 0, 0);
        acc[0][0] = __builtin_amdgcn_mfma_f32_16x16x32_bf16(afh, bfh, acc[0][0], 0, 0, 0);
      }
      __syncthreads();
    }
  }

#pragma unroll
  for (int i = 0; i < MI; ++i) {
#pragma unroll
    for (int j = 0; j < NJ; ++j) {
      const int lcol = wn + (j << 4) + (lane & 15);
#pragma unroll
      for (int rg = 0; rg < 4; ++rg) {
        const int grow = rowA0 + wm + (i << 4) + ((lane >> 4) << 2) + rg;
        float v = acc[i][j][rg];
        if (MODE == 1) {
          const int gcol = (bn << 6) + lcol;
          p.o0[(size_t)grow * 5120 + gcol] = v + p.bias[gcol];
        } else {
          const int gcol = bn * BN + lcol;
          const size_t idx = (size_t)grow * 1024 + gcol;
          if (MODE == 2) {
            float na = v + p.bias[gcol] + p.rf[idx];
            p.o0[idx] = na;
            unsigned short hb, mb, lb;
            split3(na, hb, mb, lb);
            p.oh[idx] = hb; p.om[idx] = mb; p.ol[idx] = lb;
          } else if (MODE == 3) {
            float hh = v + p.bias[gcol];
            hh = hh > 0.f ? hh : 0.f;
            unsigned short hb, mb, lb;
            split3(hh, hb, mb, lb);
            p.oh[idx] = hb; p.om[idx] = mb; p.ol[idx] = lb;
          } else if (MODE == 4) {
            float relu = v + p.bias[gcol];
            relu = relu > 0.f ? relu : 0.f;
            float nm = p.rf[idx] + relu;
            int b = grow >> 3;
            float gi = p.g1[(size_t)b * 4096 + 2048 + gcol] + p.g2[(size_t)grow * 5120 + 3072 + gcol];
            float gf = p.g1[(size_t)b * 4096 + 3072 + gcol] + p.g2[(size_t)grow * 5120 + 4096 + gcol];
            float ig = 1.f / (1.f + expf(-gi));
            float fg = 1.f / (1.f + expf(-gf));
            float nxt = ig * tanhf(nm) + fg * p.memf[idx];
            float tf = tanhf(nxt);
            p.memf[idx] = nxt;
            unsigned short hb, mb, lb;
            split3(nxt, hb, mb, lb);
            p.oh[idx] = hb; p.om[idx] = mb; p.ol[idx] = lb;
            split3(tf, hb, mb, lb);
            p.o2h[idx] = hb; p.o2m[idx] = mb; p.o2l[idx] = lb;
          }
        }
      }
    }
  }
}

__global__ __launch_bounds__(128) void attn_k(const float* qkvg, const float* xkv,
                                              unsigned short* ah, unsigned short* am,
                                              unsigned short* al) {
  const int b = blockIdx.x >> 3;
  const int h = blockIdx.x & 7;
  const int tid = threadIdx.x;
  __shared__ float sq[8][132];
  __shared__ float sk[9][132];
  __shared__ float sv[9][132];
  __shared__ double sc_[8][12];
  __shared__ float spf[8][12];

  for (int i = tid; i < 8 * 128; i += 128) {
    int s = i >> 7, d = i & 127;
    sq[s][d] = qkvg[(size_t)(b * 8 + s) * 5120 + h * 128 + d];
  }
  for (int i = tid; i < 9 * 128; i += 128) {
    int s = i >> 7, d = i & 127;
    float kv, vv;
    if (s < 8) {
      kv = qkvg[(size_t)(b * 8 + s) * 5120 + 1024 + h * 128 + d];
      vv = qkvg[(size_t)(b * 8 + s) * 5120 + 2048 + h * 128 + d];
    } else {
      kv = xkv[(size_t)b * 4096 + h * 128 + d];
      vv = xkv[(size_t)b * 4096 + 1024 + h * 128 + d];
    }
    sk[s][d] = kv; sv[s][d] = vv;
  }
  __syncthreads();
  if (tid < 72) {
    int s = tid / 9, kk = tid % 9;
    double a = 0.0;
    for (int d = 0; d < 128; ++d) a += (double)sq[s][d] * (double)sk[kk][d];
    sc_[s][kk] = a * 0.08838834764831844055;  // 1/sqrt(128)
  }
  __syncthreads();
  if (tid < 8) {
    double m = -1e300;
    for (int kk = 0; kk < 9; ++kk) m = m > sc_[tid][kk] ? m : sc_[tid][kk];
    double sum = 0.0;
    double e_[9];
    for (int kk = 0; kk < 9; ++kk) { double e = exp(sc_[tid][kk] - m); e_[kk] = e; sum += e; }
    double inv = 1.0 / sum;
    for (int kk = 0; kk < 9; ++kk) spf[tid][kk] = (float)(e_[kk] * inv);
  }
  __syncthreads();
  for (int i = tid; i < 8 * 128; i += 128) {
    int s = i >> 7, d = i & 127;
    float a = 0.f;
    for (int kk = 0; kk < 9; ++kk) a += spf[s][kk] * sv[kk][d];
    size_t idx = (size_t)(b * 8 + s) * 1024 + h * 128 + d;
    unsigned short hb, mb, lb;
    split3(a, hb, mb, lb);
    ah[idx] = hb; am[idx] = mb; al[idx] = lb;
  }
}

// fp32 [1024 (K) rows, N cols] -> 3 bf16 planes [N,1024]
__global__ __launch_bounds__(256) void wtp3_k(const float* src, unsigned short* dh,
                                              unsigned short* dm, unsigned short* dl, int N) {
  __shared__ float tile[32][33];
  const int bn = blockIdx.x << 5;
  const int bk = blockIdx.y << 5;
  const int tid = threadIdx.x;
  for (int i = tid; i < 1024; i += 256) {
    int r = i >> 5, c = i & 31;
    tile[r][c] = src[(size_t)(bk + r) * N + bn + c];
  }
  __syncthreads();
  for (int i = tid; i < 1024; i += 256) {
    int r = i >> 5, c = i & 31;
    float v = tile[c][r];
    unsigned short hb, mb, lb;
    split3(v, hb, mb, lb);
    size_t o = (size_t)(bn + r) * 1024 + bk + c;
    dh[o] = hb; dm[o] = mb; dl[o] = lb;
  }
}

__global__ __launch_bounds__(256) void biasp_k(const float* bq, const float* bk, const float* bv,
                                               const float* bw, const float* bu,
                                               float* bias1, float* xbias) {
  int i = blockIdx.x * 256 + threadIdx.x;  // 0..9215
  if (i < 5120) {
    float v;
    if (i < 1024) v = bq[i];
    else if (i < 2048) v = bk[i - 1024];
    else if (i < 3072) v = bv[i - 2048];
    else v = 0.f;
    bias1[i] = v;
  } else {
    int j = i - 5120;  // 0..4095
    float v;
    if (j < 1024) v = bk[j];
    else if (j < 2048) v = bv[j - 1024];
    else v = bw[j - 2048] + bu[j - 2048];
    xbias[j] = v;
  }
}

__global__ __launch_bounds__(256) void init_k(const float* memory, float* memF,
                                              unsigned short* mh, unsigned short* mm, unsigned short* ml,
                                              unsigned short* th, unsigned short* tm, unsigned short* tl) {
  int i = blockIdx.x * 256 + threadIdx.x;
  float v = memory[i];
  memF[i] = v;
  unsigned short hb, mb, lb;
  split3(v, hb, mb, lb);
  mh[i] = hb; mm[i] = mb; ml[i] = lb;
  float t = (float)tanh((double)v);
  split3(t, hb, mb, lb);
  th[i] = hb; tm[i] = mb; tl[i] = lb;
}

extern "C" void kernel_launch(void* const* d_in, const int* in_sizes, int n_in,
                              void* d_out, int out_size, void* d_ws, size_t ws_size,
                              hipStream_t stream) {
  const float* inputs = (const float*)d_in[0];
  const float* memory = (const float*)d_in[1];
  const float* Wq = (const float*)d_in[2];  const float* bq = (const float*)d_in[3];
  const float* Wk = (const float*)d_in[4];  const float* bk = (const float*)d_in[5];
  const float* Wv = (const float*)d_in[6];  const float* bv = (const float*)d_in[7];
  const float* Wo = (const float*)d_in[8];  const float* bo = (const float*)d_in[9];
  const float* Wm1 = (const float*)d_in[10]; const float* bm1 = (const float*)d_in[11];
  const float* Wm2 = (const float*)d_in[12]; const float* bm2 = (const float*)d_in[13];
  const float* Ww = (const float*)d_in[14]; const float* bw = (const float*)d_in[15];
  const float* Wu = (const float*)d_in[16]; const float* bu = (const float*)d_in[17];
  (void)in_sizes; (void)n_in; (void)out_size; (void)ws_size;

  char* ws = (char*)d_ws;
  const size_t MB = 1024 * 1024;
  unsigned short* catH = (unsigned short*)(ws + 0 * MB);
  unsigned short* catM = (unsigned short*)(ws + 14 * MB);
  unsigned short* catL = (unsigned short*)(ws + 28 * MB);
  unsigned short* woH  = (unsigned short*)(ws + 42 * MB);
  unsigned short* woM  = (unsigned short*)(ws + 44 * MB);
  unsigned short* woL  = (unsigned short*)(ws + 46 * MB);
  unsigned short* wm1H = (unsigned short*)(ws + 48 * MB);
  unsigned short* wm1M = (unsigned short*)(ws + 50 * MB);
  unsigned short* wm1L = (unsigned short*)(ws + 52 * MB);
  unsigned short* wm2H = (unsigned short*)(ws + 54 * MB);
  unsigned short* wm2M = (unsigned short*)(ws + 56 * MB);
  unsigned short* wm2L = (unsigned short*)(ws + 58 * MB);
  float* bias1 = (float*)(ws + 60 * MB);
  float* xbias = (float*)(ws + 60 * MB + 64 * 1024);
  float* memF  = (float*)(ws + 61 * MB);
  float* naF   = (float*)(ws + 63 * MB);
  float* qkvg  = (float*)(ws + 65 * MB);
  float* xkvF0 = (float*)(ws + 75 * MB);   // [64,4096] double-buffered
  float* xkvF1 = (float*)(ws + 92 * MB);
  unsigned short* memH  = (unsigned short*)(ws + 76 * MB);
  unsigned short* memM  = (unsigned short*)(ws + 77 * MB);
  unsigned short* memL  = (unsigned short*)(ws + 78 * MB);
  unsigned short* tmemH = (unsigned short*)(ws + 79 * MB);
  unsigned short* tmemM = (unsigned short*)(ws + 80 * MB);
  unsigned short* tmemL = (unsigned short*)(ws + 81 * MB);
  unsigned short* attnH = (unsigned short*)(ws + 82 * MB);
  unsigned short* attnM = (unsigned short*)(ws + 83 * MB);
  unsigned short* attnL = (unsigned short*)(ws + 84 * MB);
  unsigned short* naH   = (unsigned short*)(ws + 85 * MB);
  unsigned short* naM   = (unsigned short*)(ws + 86 * MB);
  unsigned short* naL   = (unsigned short*)(ws + 87 * MB);
  unsigned short* hidH  = (unsigned short*)(ws + 88 * MB);
  unsigned short* hidM  = (unsigned short*)(ws + 89 * MB);
  unsigned short* hidL  = (unsigned short*)(ws + 90 * MB);

  wtp3_k<<<dim3(32, 32), 256, 0, stream>>>(Wq, catH, catM, catL, 1024);
  wtp3_k<<<dim3(32, 32), 256, 0, stream>>>(Wk, catH + (size_t)1024 * 1024, catM + (size_t)1024 * 1024, catL + (size_t)1024 * 1024, 1024);
  wtp3_k<<<dim3(32, 32), 256, 0, stream>>>(Wv, catH + (size_t)2048 * 1024, catM + (size_t)2048 * 1024, catL + (size_t)2048 * 1024, 1024);
  wtp3_k<<<dim3(64, 32), 256, 0, stream>>>(Wu, catH + (size_t)3072 * 1024, catM + (size_t)3072 * 1024, catL + (size_t)3072 * 1024, 2048);
  wtp3_k<<<dim3(64, 32), 256, 0, stream>>>(Ww, catH + (size_t)5120 * 1024, catM + (size_t)5120 * 1024, catL + (size_t)5120 * 1024, 2048);
  wtp3_k<<<dim3(32, 32), 256, 0, stream>>>(Wo, woH, woM, woL, 1024);
  wtp3_k<<<dim3(32, 32), 256, 0, stream>>>(Wm1, wm1H, wm1M, wm1L, 1024);
  wtp3_k<<<dim3(32, 32), 256, 0, stream>>>(Wm2, wm2H, wm2M, wm2L, 1024);
  biasp_k<<<dim3(36), 256, 0, stream>>>(bq, bk, bv, bw, bu, bias1, xbias);
  init_k<<<dim3(512 * 1024 / 256), 256, 0, stream>>>(memory, memF, memH, memM, memL, tmemH, tmemM, tmemL);

  { // x-proj prologue for t=0
    GP p = {};
    p.Ax = inputs; p.strideAx = (long long)TT * 1024;
    p.Bh = catH; p.Bm = catM; p.Bl = catL;
    p.xbias = xbias; p.xkv = xkvF0;
    gemm_k<5><<<dim3(64), 256, 0, stream>>>(p);
  }

  for (int t = 0; t < TT; ++t) {
    float* xkvCur = (t & 1) ? xkvF1 : xkvF0;
    float* xkvNxt = (t & 1) ? xkvF0 : xkvF1;
    { // QKV|g2 projection (x-proj removed), flat grid 640
      GP p = {};
      p.Ah = memH; p.Am = memM; p.Al = memL;
      p.A2h = tmemH; p.A2m = tmemM; p.A2l = tmemL;
      p.Bh = catH; p.Bm = catM; p.Bl = catL;
      p.bias = bias1;
      p.o0 = qkvg;
      gemm_k<1><<<dim3(640), 256, 0, stream>>>(p);
    }
    attn_k<<<dim3(512), 128, 0, stream>>>(qkvg, xkvCur, attnH, attnM, attnL);
    {
      GP p = {};
      p.Ah = attnH; p.Am = attnM; p.Al = attnL;
      p.Bh = woH; p.Bm = woM; p.Bl = woL;
      p.bias = bo; p.rf = memF;
      p.o0 = naF; p.oh = naH; p.om = naM; p.ol = naL;
      gemm_k<2><<<dim3(512), 256, 0, stream>>>(p);
    }
    {
      GP p = {};
      p.Ah = naH; p.Am = naM; p.Al = naL;
      p.Bh = wm1H; p.Bm = wm1M; p.Bl = wm1L;
      p.bias = bm1;
      p.oh = hidH; p.om = hidM; p.ol = hidL;
      gemm_k<3><<<dim3(512), 256, 0, stream>>>(p);
    }
    { // MODE4 + fused x-proj for t+1 (blocks 512..575)
      GP p = {};
      p.Ah = hidH; p.Am = hidM; p.Al = hidL;
      p.Bh = wm2H; p.Bm = wm2M; p.Bl = wm2L;
      p.Ch = catH; p.Cm = catM; p.Cl = catL;
      p.bias = bm2; p.rf = naF;
      p.g1 = xkvCur; p.g2 = qkvg; p.memf = memF;
      p.oh = memH; p.om = memM; p.ol = memL;
      p.o2h = tmemH; p.o2m = tmemM; p.o2l = tmemL;
      p.Ax = inputs + (size_t)(t + 1) * 1024; p.strideAx = (long long)TT * 1024;
      p.xbias = xbias; p.xkv = xkvNxt;
      const int nb = (t < TT - 1) ? 576 : 512;
      gemm_k<4><<<dim3(nb), 256, 0, stream>>>(p);
    }
  }

  hipMemcpyAsync(d_out, memF, (size_t)512 * 1024 * 4, hipMemcpyDeviceToDevice, stream);
}

// Round 15
// 9968.591 us; speedup vs baseline: 1.4040x; 1.4040x over previous
//
#include <hip/hip_runtime.h>
#include <math.h>

#define TT 128

typedef __attribute__((ext_vector_type(8))) _Float16 h8v;
typedef __attribute__((ext_vector_type(4))) float f4v;

__device__ __forceinline__ void split2(float x, _Float16& h, _Float16& l) {
  h = (_Float16)x;
  float r = (x - (float)h) * 2048.0f;   // lo' = lo * 2^11 (keeps weight-lo out of fp16 denormals)
  l = (_Float16)r;
}
__device__ __forceinline__ void gload16(const void* g, void* l) {
  __builtin_amdgcn_global_load_lds(
      (const __attribute__((address_space(1))) void*)g,
      (__attribute__((address_space(3))) void*)l, 16, 0, 0);
}

#define COMBINE(a1, a2, a3) ((a1) + (a2) * 4.8828125e-4f + (a3) * 2.384185791015625e-7f)

struct GP {
  const _Float16 *Ah, *Al;      // A planes [rows,1024]
  const _Float16 *A2h, *A2l;    // MODE1: tanh(mem) planes
  const float* Ax;              // MODE1 x-role: x_t fp32
  long long strideAx;
  const _Float16 *Bh, *Bl;      // weight planes [Nrows,1024]
  const float* bias;
  const float* xbias;
  float* o0;                    // qkvg (MODE1) / naF (MODE2)
  float* xkv;                   // [64,4096] fp32
  const float* rf; const float* g1; const float* g2;
  float* memf;
  _Float16 *oh, *ol;            // split output planes
  _Float16 *o2h, *o2l;          // MODE4: tanh(mem) planes
};

// MODE 1: QKV|g2 (64x64, BK=64, flat 720, XCD-chunked; bm==8 = x-proj role)
// MODE 2/3/4: 32x32 tiles, BK=128, flat 512, XCD-chunked.
// fp16 split-2, scaled-lo, 3 accumulators (hh | hl+lh | ll).
template<int MODE>
__global__ __launch_bounds__(256) void gemm_k(GP p) {
  constexpr int BM = (MODE == 1) ? 64 : 32;
  constexpr int BN = (MODE == 1) ? 64 : 32;
  constexpr int MI = BM / 32;
  constexpr int NJ = BN / 32;

  int bn, bm;
  if (MODE == 1) {
    const int fid = blockIdx.x;                  // 0..719
    const int wid = (fid & 7) * 90 + (fid >> 3);
    bn = wid / 9; bm = wid % 9;
  } else {
    const int fid = blockIdx.x;                  // 0..511
    const int wid = (fid & 7) * 64 + (fid >> 3);
    bn = wid >> 4; bm = wid & 15;
  }
  const bool xr = (MODE == 1) && (bm == 8);
  if (MODE == 1 && xr && bn >= 64) return;

  const int tid = threadIdx.x;
  const int lane = tid & 63;
  const int wave = tid >> 6;
  const int wm = (wave >> 1) * (BM / 2);
  const int wn = (wave & 1) * (BN / 2);
  const int rowA0 = (xr ? 0 : bm) * BM;

  int wrow0;
  if (MODE == 1 && xr) wrow0 = (bn < 32) ? (1024 + (bn << 6)) : (5120 + ((bn - 32) << 6));
  else wrow0 = bn * BN;

  const _Float16* Ah = p.Ah;
  const _Float16* Al = p.Al;
  if (MODE == 1 && !xr && bn >= 48) { Ah = p.A2h; Al = p.A2l; }

  // 4096 halfs each (8KB): MODE1 = [64][64], modes 2-4 = [32][128]. Total LDS 32KB.
  __shared__ __align__(16) _Float16 lAh[4096];
  __shared__ __align__(16) _Float16 lAl[4096];
  __shared__ __align__(16) _Float16 lBh[4096];
  __shared__ __align__(16) _Float16 lBl[4096];

  f4v ac1[MI][NJ], ac2[MI][NJ], ac3[MI][NJ];
#pragma unroll
  for (int i = 0; i < MI; ++i)
#pragma unroll
    for (int j = 0; j < NJ; ++j)
#pragma unroll
      for (int r = 0; r < 4; ++r) { ac1[i][j][r] = 0.f; ac2[i][j][r] = 0.f; ac3[i][j][r] = 0.f; }

  if (MODE == 1) {
    const int lr = lane >> 3, lc = lane & 7;
    for (int kt = 0; kt < 16; ++kt) {
      const int kcol = kt << 6;
      if (!xr) {
#pragma unroll
        for (int rep = 0; rep < MI; ++rep) {
          const int rbase = (wave << 3) + (rep << 5);
          const int r = rbase + lr;
          const size_t so = (size_t)(rowA0 + r) * 1024 + kcol + ((lc ^ (r & 7)) << 3);
          gload16(Ah + so, &lAh[rbase << 6]);
          gload16(Al + so, &lAl[rbase << 6]);
        }
      } else {
#pragma unroll
        for (int h = 0; h < 2; ++h) {
          const int r = (tid >> 3) + (h << 5);
          const int sc = tid & 7;
          const float4* fp = reinterpret_cast<const float4*>(p.Ax + (size_t)r * p.strideAx + kcol + (sc << 3));
          float4 f0 = fp[0], f1 = fp[1];
          float fv[8] = { f0.x, f0.y, f0.z, f0.w, f1.x, f1.y, f1.z, f1.w };
          h8v ah, al;
#pragma unroll
          for (int e = 0; e < 8; ++e) {
            _Float16 hb, lb;
            split2(fv[e], hb, lb);
            ah[e] = hb; al[e] = lb;
          }
          const int pos = (r << 6) + ((sc ^ (r & 7)) << 3);
          *reinterpret_cast<h8v*>(&lAh[pos]) = ah;
          *reinterpret_cast<h8v*>(&lAl[pos]) = al;
        }
      }
#pragma unroll
      for (int rep = 0; rep < NJ; ++rep) {
        const int rbase = (wave << 3) + (rep << 5);
        const int r = rbase + lr;
        const size_t so = (size_t)(wrow0 + r) * 1024 + kcol + ((lc ^ (r & 7)) << 3);
        gload16(p.Bh + so, &lBh[rbase << 6]);
        gload16(p.Bl + so, &lBl[rbase << 6]);
      }
      __syncthreads();
#pragma unroll
      for (int ks = 0; ks < 2; ++ks) {
        h8v afh[MI], afl[MI], bfh[NJ], bfl[NJ];
#pragma unroll
        for (int i = 0; i < MI; ++i) {
          const int rr = wm + (i << 4) + (lane & 15);
          const int cc = (ks << 2) + (lane >> 4);
          const int pos = (rr << 6) + ((cc ^ (rr & 7)) << 3);
          afh[i] = *reinterpret_cast<const h8v*>(&lAh[pos]);
          afl[i] = *reinterpret_cast<const h8v*>(&lAl[pos]);
        }
#pragma unroll
        for (int j = 0; j < NJ; ++j) {
          const int rr = wn + (j << 4) + (lane & 15);
          const int cc = (ks << 2) + (lane >> 4);
          const int pos = (rr << 6) + ((cc ^ (rr & 7)) << 3);
          bfh[j] = *reinterpret_cast<const h8v*>(&lBh[pos]);
          bfl[j] = *reinterpret_cast<const h8v*>(&lBl[pos]);
        }
#pragma unroll
        for (int i = 0; i < MI; ++i)
#pragma unroll
          for (int j = 0; j < NJ; ++j) {
            ac3[i][j] = __builtin_amdgcn_mfma_f32_16x16x32_f16(afl[i], bfl[j], ac3[i][j], 0, 0, 0);
            ac2[i][j] = __builtin_amdgcn_mfma_f32_16x16x32_f16(afl[i], bfh[j], ac2[i][j], 0, 0, 0);
            ac2[i][j] = __builtin_amdgcn_mfma_f32_16x16x32_f16(afh[i], bfl[j], ac2[i][j], 0, 0, 0);
            ac1[i][j] = __builtin_amdgcn_mfma_f32_16x16x32_f16(afh[i], bfh[j], ac1[i][j], 0, 0, 0);
          }
      }
      __syncthreads();
    }
  } else {
    // BK=128: [32][128] tiles, 8 K-iterations.
    for (int kt = 0; kt < 8; ++kt) {
      const int kcol = kt << 7;
#pragma unroll
      for (int rep = 0; rep < 2; ++rep) {
        const int rbase = (wave << 2) + (rep << 4);
        const int r = rbase + (lane >> 4);
        const int c = lane & 15;
        const size_t soA = (size_t)(rowA0 + r) * 1024 + kcol + ((c ^ (r & 7)) << 3);
        gload16(Ah + soA, &lAh[rbase << 7]);
        gload16(Al + soA, &lAl[rbase << 7]);
        const size_t soB = (size_t)(wrow0 + r) * 1024 + kcol + ((c ^ (r & 7)) << 3);
        gload16(p.Bh + soB, &lBh[rbase << 7]);
        gload16(p.Bl + soB, &lBl[rbase << 7]);
      }
      __syncthreads();
#pragma unroll
      for (int ks = 0; ks < 4; ++ks) {
        h8v afh, afl, bfh, bfl;
        {
          const int rr = wm + (lane & 15);
          const int cc = (ks << 2) + (lane >> 4);
          const int pos = (rr << 7) + ((cc ^ (rr & 7)) << 3);
          afh = *reinterpret_cast<const h8v*>(&lAh[pos]);
          afl = *reinterpret_cast<const h8v*>(&lAl[pos]);
        }
        {
          const int rr = wn + (lane & 15);
          const int cc = (ks << 2) + (lane >> 4);
          const int pos = (rr << 7) + ((cc ^ (rr & 7)) << 3);
          bfh = *reinterpret_cast<const h8v*>(&lBh[pos]);
          bfl = *reinterpret_cast<const h8v*>(&lBl[pos]);
        }
        ac3[0][0] = __builtin_amdgcn_mfma_f32_16x16x32_f16(afl, bfl, ac3[0][0], 0, 0, 0);
        ac2[0][0] = __builtin_amdgcn_mfma_f32_16x16x32_f16(afl, bfh, ac2[0][0], 0, 0, 0);
        ac2[0][0] = __builtin_amdgcn_mfma_f32_16x16x32_f16(afh, bfl, ac2[0][0], 0, 0, 0);
        ac1[0][0] = __builtin_amdgcn_mfma_f32_16x16x32_f16(afh, bfh, ac1[0][0], 0, 0, 0);
      }
      __syncthreads();
    }
  }

#pragma unroll
  for (int i = 0; i < MI; ++i) {
#pragma unroll
    for (int j = 0; j < NJ; ++j) {
      const int lcol = wn + (j << 4) + (lane & 15);
#pragma unroll
      for (int rg = 0; rg < 4; ++rg) {
        const int grow = rowA0 + wm + (i << 4) + ((lane >> 4) << 2) + rg;
        float v = COMBINE(ac1[i][j][rg], ac2[i][j][rg], ac3[i][j][rg]);
        if (MODE == 1) {
          if (xr) {
            const int gcol = (bn < 32) ? ((bn << 6) + lcol) : (2048 + ((bn - 32) << 6) + lcol);
            p.xkv[(size_t)grow * 4096 + gcol] = v + p.xbias[gcol];
          } else {
            const int gcol = (bn << 6) + lcol;
            p.o0[(size_t)grow * 5120 + gcol] = v + p.bias[gcol];
          }
        } else {
          const int gcol = bn * BN + lcol;
          const size_t idx = (size_t)grow * 1024 + gcol;
          if (MODE == 2) {
            float na = v + p.bias[gcol] + p.rf[idx];
            p.o0[idx] = na;
            _Float16 hb, lb;
            split2(na, hb, lb);
            p.oh[idx] = hb; p.ol[idx] = lb;
          } else if (MODE == 3) {
            float hh = v + p.bias[gcol];
            hh = hh > 0.f ? hh : 0.f;
            _Float16 hb, lb;
            split2(hh, hb, lb);
            p.oh[idx] = hb; p.ol[idx] = lb;
          } else if (MODE == 4) {
            float relu = v + p.bias[gcol];
            relu = relu > 0.f ? relu : 0.f;
            float nm = p.rf[idx] + relu;
            int b = grow >> 3;
            float gi = p.g1[(size_t)b * 4096 + 2048 + gcol] + p.g2[(size_t)grow * 5120 + 3072 + gcol];
            float gf = p.g1[(size_t)b * 4096 + 3072 + gcol] + p.g2[(size_t)grow * 5120 + 4096 + gcol];
            float ig = 1.f / (1.f + expf(-gi));
            float fg = 1.f / (1.f + expf(-gf));
            float nxt = ig * tanhf(nm) + fg * p.memf[idx];
            float tf = tanhf(nxt);
            p.memf[idx] = nxt;
            _Float16 hb, lb;
            split2(nxt, hb, lb);
            p.oh[idx] = hb; p.ol[idx] = lb;
            split2(tf, hb, lb);
            p.o2h[idx] = hb; p.o2l[idx] = lb;
          }
        }
      }
    }
  }
}

__global__ __launch_bounds__(128) void attn_k(const float* qkvg, const float* xkv,
                                              _Float16* ah, _Float16* al) {
  const int b = blockIdx.x >> 3;
  const int h = blockIdx.x & 7;
  const int tid = threadIdx.x;
  __shared__ float sq[8][132];
  __shared__ float sk[9][132];
  __shared__ float sv[9][132];
  __shared__ double sc_[8][12];
  __shared__ float spf[8][12];

  for (int i = tid; i < 8 * 128; i += 128) {
    int s = i >> 7, d = i & 127;
    sq[s][d] = qkvg[(size_t)(b * 8 + s) * 5120 + h * 128 + d];
  }
  for (int i = tid; i < 9 * 128; i += 128) {
    int s = i >> 7, d = i & 127;
    float kv, vv;
    if (s < 8) {
      kv = qkvg[(size_t)(b * 8 + s) * 5120 + 1024 + h * 128 + d];
      vv = qkvg[(size_t)(b * 8 + s) * 5120 + 2048 + h * 128 + d];
    } else {
      kv = xkv[(size_t)b * 4096 + h * 128 + d];
      vv = xkv[(size_t)b * 4096 + 1024 + h * 128 + d];
    }
    sk[s][d] = kv; sv[s][d] = vv;
  }
  __syncthreads();
  if (tid < 72) {
    int s = tid / 9, kk = tid % 9;
    double a = 0.0;
    for (int d = 0; d < 128; ++d) a += (double)sq[s][d] * (double)sk[kk][d];
    sc_[s][kk] = a * 0.08838834764831844055;  // 1/sqrt(128)
  }
  __syncthreads();
  if (tid < 8) {
    double m = -1e300;
    for (int kk = 0; kk < 9; ++kk) m = m > sc_[tid][kk] ? m : sc_[tid][kk];
    double sum = 0.0;
    double e_[9];
    for (int kk = 0; kk < 9; ++kk) { double e = exp(sc_[tid][kk] - m); e_[kk] = e; sum += e; }
    double inv = 1.0 / sum;
    for (int kk = 0; kk < 9; ++kk) spf[tid][kk] = (float)(e_[kk] * inv);
  }
  __syncthreads();
  for (int i = tid; i < 8 * 128; i += 128) {
    int s = i >> 7, d = i & 127;
    float a = 0.f;
    for (int kk = 0; kk < 9; ++kk) a += spf[s][kk] * sv[kk][d];
    size_t idx = (size_t)(b * 8 + s) * 1024 + h * 128 + d;
    _Float16 hb, lb;
    split2(a, hb, lb);
    ah[idx] = hb; al[idx] = lb;
  }
}

// fp32 [1024 (K) rows, N cols] -> 2 fp16 planes [N,1024] (hi, lo*2^11)
__global__ __launch_bounds__(256) void wtp2_k(const float* src, _Float16* dh, _Float16* dl, int N) {
  __shared__ float tile[32][33];
  const int bn = blockIdx.x << 5;
  const int bk = blockIdx.y << 5;
  const int tid = threadIdx.x;
  for (int i = tid; i < 1024; i += 256) {
    int r = i >> 5, c = i & 31;
    tile[r][c] = src[(size_t)(bk + r) * N + bn + c];
  }
  __syncthreads();
  for (int i = tid; i < 1024; i += 256) {
    int r = i >> 5, c = i & 31;
    float v = tile[c][r];
    _Float16 hb, lb;
    split2(v, hb, lb);
    size_t o = (size_t)(bn + r) * 1024 + bk + c;
    dh[o] = hb; dl[o] = lb;
  }
}

__global__ __launch_bounds__(256) void biasp_k(const float* bq, const float* bk, const float* bv,
                                               const float* bw, const float* bu,
                                               float* bias1, float* xbias) {
  int i = blockIdx.x * 256 + threadIdx.x;  // 0..9215
  if (i < 5120) {
    float v;
    if (i < 1024) v = bq[i];
    else if (i < 2048) v = bk[i - 1024];
    else if (i < 3072) v = bv[i - 2048];
    else v = 0.f;
    bias1[i] = v;
  } else {
    int j = i - 5120;  // 0..4095
    float v;
    if (j < 1024) v = bk[j];
    else if (j < 2048) v = bv[j - 1024];
    else v = bw[j - 2048] + bu[j - 2048];
    xbias[j] = v;
  }
}

__global__ __launch_bounds__(256) void init_k(const float* memory, float* memF,
                                              _Float16* mh, _Float16* ml,
                                              _Float16* th, _Float16* tl) {
  int i = blockIdx.x * 256 + threadIdx.x;
  float v = memory[i];
  memF[i] = v;
  _Float16 hb, lb;
  split2(v, hb, lb);
  mh[i] = hb; ml[i] = lb;
  float t = (float)tanh((double)v);
  split2(t, hb, lb);
  th[i] = hb; tl[i] = lb;
}

extern "C" void kernel_launch(void* const* d_in, const int* in_sizes, int n_in,
                              void* d_out, int out_size, void* d_ws, size_t ws_size,
                              hipStream_t stream) {
  const float* inputs = (const float*)d_in[0];
  const float* memory = (const float*)d_in[1];
  const float* Wq = (const float*)d_in[2];  const float* bq = (const float*)d_in[3];
  const float* Wk = (const float*)d_in[4];  const float* bk = (const float*)d_in[5];
  const float* Wv = (const float*)d_in[6];  const float* bv = (const float*)d_in[7];
  const float* Wo = (const float*)d_in[8];  const float* bo = (const float*)d_in[9];
  const float* Wm1 = (const float*)d_in[10]; const float* bm1 = (const float*)d_in[11];
  const float* Wm2 = (const float*)d_in[12]; const float* bm2 = (const float*)d_in[13];
  const float* Ww = (const float*)d_in[14]; const float* bw = (const float*)d_in[15];
  const float* Wu = (const float*)d_in[16]; const float* bu = (const float*)d_in[17];
  (void)in_sizes; (void)n_in; (void)out_size; (void)ws_size;

  char* ws = (char*)d_ws;
  const size_t MB = 1024 * 1024;
  // cat rows: [Wq 0..1023 | Wk 1024..2047 | Wv 2048..3071 | Wu 3072..5119 | Ww 5120..7167]
  _Float16* catH = (_Float16*)(ws + 0 * MB);    // 14MB each
  _Float16* catL = (_Float16*)(ws + 14 * MB);
  _Float16* woH  = (_Float16*)(ws + 28 * MB);   // 2MB each
  _Float16* woL  = (_Float16*)(ws + 30 * MB);
  _Float16* wm1H = (_Float16*)(ws + 32 * MB);
  _Float16* wm1L = (_Float16*)(ws + 34 * MB);
  _Float16* wm2H = (_Float16*)(ws + 36 * MB);
  _Float16* wm2L = (_Float16*)(ws + 38 * MB);
  float* bias1 = (float*)(ws + 40 * MB);                  // [5120]
  float* xbias = (float*)(ws + 40 * MB + 64 * 1024);      // [4096]
  float* memF  = (float*)(ws + 41 * MB);                  // [512,1024] fp32
  float* naF   = (float*)(ws + 43 * MB);
  float* qkvg  = (float*)(ws + 45 * MB);                  // [512,5120] 10MB
  float* xkvF  = (float*)(ws + 55 * MB);                  // [64,4096]
  _Float16* memH  = (_Float16*)(ws + 56 * MB);            // [512,1024] fp16, 1MB each
  _Float16* memL  = (_Float16*)(ws + 57 * MB);
  _Float16* tmemH = (_Float16*)(ws + 58 * MB);
  _Float16* tmemL = (_Float16*)(ws + 59 * MB);
  _Float16* attnH = (_Float16*)(ws + 60 * MB);
  _Float16* attnL = (_Float16*)(ws + 61 * MB);
  _Float16* naH   = (_Float16*)(ws + 62 * MB);
  _Float16* naL   = (_Float16*)(ws + 63 * MB);
  _Float16* hidH  = (_Float16*)(ws + 64 * MB);
  _Float16* hidL  = (_Float16*)(ws + 65 * MB);

  wtp2_k<<<dim3(32, 32), 256, 0, stream>>>(Wq, catH, catL, 1024);
  wtp2_k<<<dim3(32, 32), 256, 0, stream>>>(Wk, catH + (size_t)1024 * 1024, catL + (size_t)1024 * 1024, 1024);
  wtp2_k<<<dim3(32, 32), 256, 0, stream>>>(Wv, catH + (size_t)2048 * 1024, catL + (size_t)2048 * 1024, 1024);
  wtp2_k<<<dim3(64, 32), 256, 0, stream>>>(Wu, catH + (size_t)3072 * 1024, catL + (size_t)3072 * 1024, 2048);
  wtp2_k<<<dim3(64, 32), 256, 0, stream>>>(Ww, catH + (size_t)5120 * 1024, catL + (size_t)5120 * 1024, 2048);
  wtp2_k<<<dim3(32, 32), 256, 0, stream>>>(Wo, woH, woL, 1024);
  wtp2_k<<<dim3(32, 32), 256, 0, stream>>>(Wm1, wm1H, wm1L, 1024);
  wtp2_k<<<dim3(32, 32), 256, 0, stream>>>(Wm2, wm2H, wm2L, 1024);
  biasp_k<<<dim3(36), 256, 0, stream>>>(bq, bk, bv, bw, bu, bias1, xbias);
  init_k<<<dim3(512 * 1024 / 256), 256, 0, stream>>>(memory, memF, memH, memL, tmemH, tmemL);

  for (int t = 0; t < TT; ++t) {
    { // QKV|g2 + fused x-proj, flat grid 720
      GP p = {};
      p.Ah = memH; p.Al = memL;
      p.A2h = tmemH; p.A2l = tmemL;
      p.Ax = inputs + (size_t)t * 1024; p.strideAx = (long long)TT * 1024;
      p.Bh = catH; p.Bl = catL;
      p.bias = bias1; p.xbias = xbias;
      p.o0 = qkvg; p.xkv = xkvF;
      gemm_k<1><<<dim3(720), 256, 0, stream>>>(p);
    }
    attn_k<<<dim3(512), 128, 0, stream>>>(qkvg, xkvF, attnH, attnL);
    { // attn @ Wo + bo + mem
      GP p = {};
      p.Ah = attnH; p.Al = attnL;
      p.Bh = woH; p.Bl = woL;
      p.bias = bo; p.rf = memF;
      p.o0 = naF; p.oh = naH; p.ol = naL;
      gemm_k<2><<<dim3(512), 256, 0, stream>>>(p);
    }
    { // relu(na @ Wm1 + bm1)
      GP p = {};
      p.Ah = naH; p.Al = naL;
      p.Bh = wm1H; p.Bl = wm1L;
      p.bias = bm1;
      p.oh = hidH; p.ol = hidL;
      gemm_k<3><<<dim3(512), 256, 0, stream>>>(p);
    }
    { // hid @ Wm2 + gates -> mem
      GP p = {};
      p.Ah = hidH; p.Al = hidL;
      p.Bh = wm2H; p.Bl = wm2L;
      p.bias = bm2; p.rf = naF;
      p.g1 = xkvF; p.g2 = qkvg; p.memf = memF;
      p.oh = memH; p.ol = memL;
      p.o2h = tmemH; p.o2l = tmemL;
      gemm_k<4><<<dim3(512), 256, 0, stream>>>(p);
    }
  }

  hipMemcpyAsync(d_out, memF, (size_t)512 * 1024 * 4, hipMemcpyDeviceToDevice, stream);
}

// Round 16
// 9318.424 us; speedup vs baseline: 1.5020x; 1.0698x over previous
//
#include <hip/hip_runtime.h>
#include <math.h>

#define TT 128

typedef __attribute__((ext_vector_type(8))) _Float16 h8v;
typedef __attribute__((ext_vector_type(4))) float f4v;

__device__ __forceinline__ void split2(float x, _Float16& h, _Float16& l) {
  h = (_Float16)x;
  float r = (x - (float)h) * 2048.0f;   // lo' = lo * 2^11 (keeps lo out of fp16 denormals)
  l = (_Float16)r;
}
__device__ __forceinline__ void gload16(const void* g, void* l) {
  __builtin_amdgcn_global_load_lds(
      (const __attribute__((address_space(1))) void*)g,
      (__attribute__((address_space(3))) void*)l, 16, 0, 0);
}

#define COMBINE(a1, a2) ((a1) + (a2) * 4.8828125e-4f)

struct GP {
  const _Float16 *Ah, *Al;      // A planes [rows,1024]
  const _Float16 *A2h, *A2l;    // MODE1: tanh(mem) planes
  const float* Ax;              // MODE1 x-role: x_t fp32
  long long strideAx;
  const _Float16 *Bh, *Bl;      // weight planes [Nrows,1024]
  const float* bias;
  const float* xbias;
  float* o0;                    // qkvg (MODE1) / naF (MODE2)
  float* xkv;                   // [64,4096] fp32
  const float* rf; const float* g1; const float* g2;
  float* memf;
  _Float16 *oh, *ol;            // split output planes
  _Float16 *o2h, *o2l;          // MODE4: tanh(mem) planes
};

// MODE 1: QKV|g2 (64x64, BK=64, flat 720, XCD-chunked; bm==8 = x-proj role)
// MODE 2/3/4: 32x32 tiles, BK=128, flat 512, XCD-chunked.
// fp16 split-2, scaled-lo, 2 accumulators (hh | hl+lh); ll dropped (~2^-22 rel, under fp32 floor).
template<int MODE>
__global__ __launch_bounds__(256) void gemm_k(GP p) {
  constexpr int BM = (MODE == 1) ? 64 : 32;
  constexpr int BN = (MODE == 1) ? 64 : 32;
  constexpr int MI = BM / 32;
  constexpr int NJ = BN / 32;

  int bn, bm;
  if (MODE == 1) {
    const int fid = blockIdx.x;                  // 0..719
    const int wid = (fid & 7) * 90 + (fid >> 3);
    bn = wid / 9; bm = wid % 9;
  } else {
    const int fid = blockIdx.x;                  // 0..511
    const int wid = (fid & 7) * 64 + (fid >> 3);
    bn = wid >> 4; bm = wid & 15;
  }
  const bool xr = (MODE == 1) && (bm == 8);
  if (MODE == 1 && xr && bn >= 64) return;

  const int tid = threadIdx.x;
  const int lane = tid & 63;
  const int wave = tid >> 6;
  const int wm = (wave >> 1) * (BM / 2);
  const int wn = (wave & 1) * (BN / 2);
  const int rowA0 = (xr ? 0 : bm) * BM;

  int wrow0;
  if (MODE == 1 && xr) wrow0 = (bn < 32) ? (1024 + (bn << 6)) : (5120 + ((bn - 32) << 6));
  else wrow0 = bn * BN;

  const _Float16* Ah = p.Ah;
  const _Float16* Al = p.Al;
  if (MODE == 1 && !xr && bn >= 48) { Ah = p.A2h; Al = p.A2l; }

  __shared__ __align__(16) _Float16 lAh[4096];
  __shared__ __align__(16) _Float16 lAl[4096];
  __shared__ __align__(16) _Float16 lBh[4096];
  __shared__ __align__(16) _Float16 lBl[4096];

  f4v ac1[MI][NJ], ac2[MI][NJ];
#pragma unroll
  for (int i = 0; i < MI; ++i)
#pragma unroll
    for (int j = 0; j < NJ; ++j)
#pragma unroll
      for (int r = 0; r < 4; ++r) { ac1[i][j][r] = 0.f; ac2[i][j][r] = 0.f; }

  if (MODE == 1) {
    const int lr = lane >> 3, lc = lane & 7;
    for (int kt = 0; kt < 16; ++kt) {
      const int kcol = kt << 6;
      if (!xr) {
#pragma unroll
        for (int rep = 0; rep < MI; ++rep) {
          const int rbase = (wave << 3) + (rep << 5);
          const int r = rbase + lr;
          const size_t so = (size_t)(rowA0 + r) * 1024 + kcol + ((lc ^ (r & 7)) << 3);
          gload16(Ah + so, &lAh[rbase << 6]);
          gload16(Al + so, &lAl[rbase << 6]);
        }
      } else {
#pragma unroll
        for (int h = 0; h < 2; ++h) {
          const int r = (tid >> 3) + (h << 5);
          const int sc = tid & 7;
          const float4* fp = reinterpret_cast<const float4*>(p.Ax + (size_t)r * p.strideAx + kcol + (sc << 3));
          float4 f0 = fp[0], f1 = fp[1];
          float fv[8] = { f0.x, f0.y, f0.z, f0.w, f1.x, f1.y, f1.z, f1.w };
          h8v ah, al;
#pragma unroll
          for (int e = 0; e < 8; ++e) {
            _Float16 hb, lb;
            split2(fv[e], hb, lb);
            ah[e] = hb; al[e] = lb;
          }
          const int pos = (r << 6) + ((sc ^ (r & 7)) << 3);
          *reinterpret_cast<h8v*>(&lAh[pos]) = ah;
          *reinterpret_cast<h8v*>(&lAl[pos]) = al;
        }
      }
#pragma unroll
      for (int rep = 0; rep < NJ; ++rep) {
        const int rbase = (wave << 3) + (rep << 5);
        const int r = rbase + lr;
        const size_t so = (size_t)(wrow0 + r) * 1024 + kcol + ((lc ^ (r & 7)) << 3);
        gload16(p.Bh + so, &lBh[rbase << 6]);
        gload16(p.Bl + so, &lBl[rbase << 6]);
      }
      __syncthreads();
#pragma unroll
      for (int ks = 0; ks < 2; ++ks) {
        h8v afh[MI], afl[MI], bfh[NJ], bfl[NJ];
#pragma unroll
        for (int i = 0; i < MI; ++i) {
          const int rr = wm + (i << 4) + (lane & 15);
          const int cc = (ks << 2) + (lane >> 4);
          const int pos = (rr << 6) + ((cc ^ (rr & 7)) << 3);
          afh[i] = *reinterpret_cast<const h8v*>(&lAh[pos]);
          afl[i] = *reinterpret_cast<const h8v*>(&lAl[pos]);
        }
#pragma unroll
        for (int j = 0; j < NJ; ++j) {
          const int rr = wn + (j << 4) + (lane & 15);
          const int cc = (ks << 2) + (lane >> 4);
          const int pos = (rr << 6) + ((cc ^ (rr & 7)) << 3);
          bfh[j] = *reinterpret_cast<const h8v*>(&lBh[pos]);
          bfl[j] = *reinterpret_cast<const h8v*>(&lBl[pos]);
        }
#pragma unroll
        for (int i = 0; i < MI; ++i)
#pragma unroll
          for (int j = 0; j < NJ; ++j) {
            ac2[i][j] = __builtin_amdgcn_mfma_f32_16x16x32_f16(afl[i], bfh[j], ac2[i][j], 0, 0, 0);
            ac2[i][j] = __builtin_amdgcn_mfma_f32_16x16x32_f16(afh[i], bfl[j], ac2[i][j], 0, 0, 0);
            ac1[i][j] = __builtin_amdgcn_mfma_f32_16x16x32_f16(afh[i], bfh[j], ac1[i][j], 0, 0, 0);
          }
      }
      __syncthreads();
    }
  } else {
    for (int kt = 0; kt < 8; ++kt) {
      const int kcol = kt << 7;
#pragma unroll
      for (int rep = 0; rep < 2; ++rep) {
        const int rbase = (wave << 2) + (rep << 4);
        const int r = rbase + (lane >> 4);
        const int c = lane & 15;
        const size_t soA = (size_t)(rowA0 + r) * 1024 + kcol + ((c ^ (r & 7)) << 3);
        gload16(Ah + soA, &lAh[rbase << 7]);
        gload16(Al + soA, &lAl[rbase << 7]);
        const size_t soB = (size_t)(wrow0 + r) * 1024 + kcol + ((c ^ (r & 7)) << 3);
        gload16(p.Bh + soB, &lBh[rbase << 7]);
        gload16(p.Bl + soB, &lBl[rbase << 7]);
      }
      __syncthreads();
#pragma unroll
      for (int ks = 0; ks < 4; ++ks) {
        h8v afh, afl, bfh, bfl;
        {
          const int rr = wm + (lane & 15);
          const int cc = (ks << 2) + (lane >> 4);
          const int pos = (rr << 7) + ((cc ^ (rr & 7)) << 3);
          afh = *reinterpret_cast<const h8v*>(&lAh[pos]);
          afl = *reinterpret_cast<const h8v*>(&lAl[pos]);
        }
        {
          const int rr = wn + (lane & 15);
          const int cc = (ks << 2) + (lane >> 4);
          const int pos = (rr << 7) + ((cc ^ (rr & 7)) << 3);
          bfh = *reinterpret_cast<const h8v*>(&lBh[pos]);
          bfl = *reinterpret_cast<const h8v*>(&lBl[pos]);
        }
        ac2[0][0] = __builtin_amdgcn_mfma_f32_16x16x32_f16(afl, bfh, ac2[0][0], 0, 0, 0);
        ac2[0][0] = __builtin_amdgcn_mfma_f32_16x16x32_f16(afh, bfl, ac2[0][0], 0, 0, 0);
        ac1[0][0] = __builtin_amdgcn_mfma_f32_16x16x32_f16(afh, bfh, ac1[0][0], 0, 0, 0);
      }
      __syncthreads();
    }
  }

#pragma unroll
  for (int i = 0; i < MI; ++i) {
#pragma unroll
    for (int j = 0; j < NJ; ++j) {
      const int lcol = wn + (j << 4) + (lane & 15);
#pragma unroll
      for (int rg = 0; rg < 4; ++rg) {
        const int grow = rowA0 + wm + (i << 4) + ((lane >> 4) << 2) + rg;
        float v = COMBINE(ac1[i][j][rg], ac2[i][j][rg]);
        if (MODE == 1) {
          if (xr) {
            const int gcol = (bn < 32) ? ((bn << 6) + lcol) : (2048 + ((bn - 32) << 6) + lcol);
            p.xkv[(size_t)grow * 4096 + gcol] = v + p.xbias[gcol];
          } else {
            const int gcol = (bn << 6) + lcol;
            p.o0[(size_t)grow * 5120 + gcol] = v + p.bias[gcol];
          }
        } else {
          const int gcol = bn * BN + lcol;
          const size_t idx = (size_t)grow * 1024 + gcol;
          if (MODE == 2) {
            float na = v + p.bias[gcol] + p.rf[idx];
            p.o0[idx] = na;
            _Float16 hb, lb;
            split2(na, hb, lb);
            p.oh[idx] = hb; p.ol[idx] = lb;
          } else if (MODE == 3) {
            float hh = v + p.bias[gcol];
            hh = hh > 0.f ? hh : 0.f;
            _Float16 hb, lb;
            split2(hh, hb, lb);
            p.oh[idx] = hb; p.ol[idx] = lb;
          } else if (MODE == 4) {
            float relu = v + p.bias[gcol];
            relu = relu > 0.f ? relu : 0.f;
            float nm = p.rf[idx] + relu;
            int b = grow >> 3;
            float gi = p.g1[(size_t)b * 4096 + 2048 + gcol] + p.g2[(size_t)grow * 5120 + 3072 + gcol];
            float gf = p.g1[(size_t)b * 4096 + 3072 + gcol] + p.g2[(size_t)grow * 5120 + 4096 + gcol];
            float ig = 1.f / (1.f + expf(-gi));
            float fg = 1.f / (1.f + expf(-gf));
            float nxt = ig * tanhf(nm) + fg * p.memf[idx];
            float tf = tanhf(nxt);
            p.memf[idx] = nxt;
            _Float16 hb, lb;
            split2(nxt, hb, lb);
            p.oh[idx] = hb; p.ol[idx] = lb;
            split2(tf, hb, lb);
            p.o2h[idx] = hb; p.o2l[idx] = lb;
          }
        }
      }
    }
  }
}

__global__ __launch_bounds__(128) void attn_k(const float* qkvg, const float* xkv,
                                              _Float16* ah, _Float16* al) {
  const int b = blockIdx.x >> 3;
  const int h = blockIdx.x & 7;
  const int tid = threadIdx.x;
  __shared__ float sq[8][132];
  __shared__ float sk[9][132];
  __shared__ float sv[9][132];
  __shared__ float sc_[8][12];
  __shared__ float spf[8][12];

  for (int i = tid; i < 8 * 128; i += 128) {
    int s = i >> 7, d = i & 127;
    sq[s][d] = qkvg[(size_t)(b * 8 + s) * 5120 + h * 128 + d];
  }
  for (int i = tid; i < 9 * 128; i += 128) {
    int s = i >> 7, d = i & 127;
    float kv, vv;
    if (s < 8) {
      kv = qkvg[(size_t)(b * 8 + s) * 5120 + 1024 + h * 128 + d];
      vv = qkvg[(size_t)(b * 8 + s) * 5120 + 2048 + h * 128 + d];
    } else {
      kv = xkv[(size_t)b * 4096 + h * 128 + d];
      vv = xkv[(size_t)b * 4096 + 1024 + h * 128 + d];
    }
    sk[s][d] = kv; sv[s][d] = vv;
  }
  __syncthreads();
  if (tid < 72) {
    int s = tid / 9, kk = tid % 9;
    float a = 0.f;
    for (int d = 0; d < 128; ++d) a += sq[s][d] * sk[kk][d];
    sc_[s][kk] = a * 0.088388347648318447f;  // 1/sqrt(128)
  }
  __syncthreads();
  if (tid < 8) {
    float m = -1e30f;
    for (int kk = 0; kk < 9; ++kk) m = fmaxf(m, sc_[tid][kk]);
    float sum = 0.f;
    float e_[9];
    for (int kk = 0; kk < 9; ++kk) { float e = expf(sc_[tid][kk] - m); e_[kk] = e; sum += e; }
    float inv = 1.f / sum;
    for (int kk = 0; kk < 9; ++kk) spf[tid][kk] = e_[kk] * inv;
  }
  __syncthreads();
  for (int i = tid; i < 8 * 128; i += 128) {
    int s = i >> 7, d = i & 127;
    float a = 0.f;
    for (int kk = 0; kk < 9; ++kk) a += spf[s][kk] * sv[kk][d];
    size_t idx = (size_t)(b * 8 + s) * 1024 + h * 128 + d;
    _Float16 hb, lb;
    split2(a, hb, lb);
    ah[idx] = hb; al[idx] = lb;
  }
}

// fp32 [1024 (K) rows, N cols] -> 2 fp16 planes [N,1024] (hi, lo*2^11)
__global__ __launch_bounds__(256) void wtp2_k(const float* src, _Float16* dh, _Float16* dl, int N) {
  __shared__ float tile[32][33];
  const int bn = blockIdx.x << 5;
  const int bk = blockIdx.y << 5;
  const int tid = threadIdx.x;
  for (int i = tid; i < 1024; i += 256) {
    int r = i >> 5, c = i & 31;
    tile[r][c] = src[(size_t)(bk + r) * N + bn + c];
  }
  __syncthreads();
  for (int i = tid; i < 1024; i += 256) {
    int r = i >> 5, c = i & 31;
    float v = tile[c][r];
    _Float16 hb, lb;
    split2(v, hb, lb);
    size_t o = (size_t)(bn + r) * 1024 + bk + c;
    dh[o] = hb; dl[o] = lb;
  }
}

__global__ __launch_bounds__(256) void biasp_k(const float* bq, const float* bk, const float* bv,
                                               const float* bw, const float* bu,
                                               float* bias1, float* xbias) {
  int i = blockIdx.x * 256 + threadIdx.x;  // 0..9215
  if (i < 5120) {
    float v;
    if (i < 1024) v = bq[i];
    else if (i < 2048) v = bk[i - 1024];
    else if (i < 3072) v = bv[i - 2048];
    else v = 0.f;
    bias1[i] = v;
  } else {
    int j = i - 5120;  // 0..4095
    float v;
    if (j < 1024) v = bk[j];
    else if (j < 2048) v = bv[j - 1024];
    else v = bw[j - 2048] + bu[j - 2048];
    xbias[j] = v;
  }
}

__global__ __launch_bounds__(256) void init_k(const float* memory, float* memF,
                                              _Float16* mh, _Float16* ml,
                                              _Float16* th, _Float16* tl) {
  int i = blockIdx.x * 256 + threadIdx.x;
  float v = memory[i];
  memF[i] = v;
  _Float16 hb, lb;
  split2(v, hb, lb);
  mh[i] = hb; ml[i] = lb;
  float t = (float)tanh((double)v);
  split2(t, hb, lb);
  th[i] = hb; tl[i] = lb;
}

extern "C" void kernel_launch(void* const* d_in, const int* in_sizes, int n_in,
                              void* d_out, int out_size, void* d_ws, size_t ws_size,
                              hipStream_t stream) {
  const float* inputs = (const float*)d_in[0];
  const float* memory = (const float*)d_in[1];
  const float* Wq = (const float*)d_in[2];  const float* bq = (const float*)d_in[3];
  const float* Wk = (const float*)d_in[4];  const float* bk = (const float*)d_in[5];
  const float* Wv = (const float*)d_in[6];  const float* bv = (const float*)d_in[7];
  const float* Wo = (const float*)d_in[8];  const float* bo = (const float*)d_in[9];
  const float* Wm1 = (const float*)d_in[10]; const float* bm1 = (const float*)d_in[11];
  const float* Wm2 = (const float*)d_in[12]; const float* bm2 = (const float*)d_in[13];
  const float* Ww = (const float*)d_in[14]; const float* bw = (const float*)d_in[15];
  const float* Wu = (const float*)d_in[16]; const float* bu = (const float*)d_in[17];
  (void)in_sizes; (void)n_in; (void)out_size; (void)ws_size;

  char* ws = (char*)d_ws;
  const size_t MB = 1024 * 1024;
  _Float16* catH = (_Float16*)(ws + 0 * MB);
  _Float16* catL = (_Float16*)(ws + 14 * MB);
  _Float16* woH  = (_Float16*)(ws + 28 * MB);
  _Float16* woL  = (_Float16*)(ws + 30 * MB);
  _Float16* wm1H = (_Float16*)(ws + 32 * MB);
  _Float16* wm1L = (_Float16*)(ws + 34 * MB);
  _Float16* wm2H = (_Float16*)(ws + 36 * MB);
  _Float16* wm2L = (_Float16*)(ws + 38 * MB);
  float* bias1 = (float*)(ws + 40 * MB);
  float* xbias = (float*)(ws + 40 * MB + 64 * 1024);
  float* memF  = (float*)(ws + 41 * MB);
  float* naF   = (float*)(ws + 43 * MB);
  float* qkvg  = (float*)(ws + 45 * MB);
  float* xkvF  = (float*)(ws + 55 * MB);
  _Float16* memH  = (_Float16*)(ws + 56 * MB);
  _Float16* memL  = (_Float16*)(ws + 57 * MB);
  _Float16* tmemH = (_Float16*)(ws + 58 * MB);
  _Float16* tmemL = (_Float16*)(ws + 59 * MB);
  _Float16* attnH = (_Float16*)(ws + 60 * MB);
  _Float16* attnL = (_Float16*)(ws + 61 * MB);
  _Float16* naH   = (_Float16*)(ws + 62 * MB);
  _Float16* naL   = (_Float16*)(ws + 63 * MB);
  _Float16* hidH  = (_Float16*)(ws + 64 * MB);
  _Float16* hidL  = (_Float16*)(ws + 65 * MB);

  wtp2_k<<<dim3(32, 32), 256, 0, stream>>>(Wq, catH, catL, 1024);
  wtp2_k<<<dim3(32, 32), 256, 0, stream>>>(Wk, catH + (size_t)1024 * 1024, catL + (size_t)1024 * 1024, 1024);
  wtp2_k<<<dim3(32, 32), 256, 0, stream>>>(Wv, catH + (size_t)2048 * 1024, catL + (size_t)2048 * 1024, 1024);
  wtp2_k<<<dim3(64, 32), 256, 0, stream>>>(Wu, catH + (size_t)3072 * 1024, catL + (size_t)3072 * 1024, 2048);
  wtp2_k<<<dim3(64, 32), 256, 0, stream>>>(Ww, catH + (size_t)5120 * 1024, catL + (size_t)5120 * 1024, 2048);
  wtp2_k<<<dim3(32, 32), 256, 0, stream>>>(Wo, woH, woL, 1024);
  wtp2_k<<<dim3(32, 32), 256, 0, stream>>>(Wm1, wm1H, wm1L, 1024);
  wtp2_k<<<dim3(32, 32), 256, 0, stream>>>(Wm2, wm2H, wm2L, 1024);
  biasp_k<<<dim3(36), 256, 0, stream>>>(bq, bk, bv, bw, bu, bias1, xbias);
  init_k<<<dim3(512 * 1024 / 256), 256, 0, stream>>>(memory, memF, memH, memL, tmemH, tmemL);

  for (int t = 0; t < TT; ++t) {
    { // QKV|g2 + fused x-proj, flat grid 720
      GP p = {};
      p.Ah = memH; p.Al = memL;
      p.A2h = tmemH; p.A2l = tmemL;
      p.Ax = inputs + (size_t)t * 1024; p.strideAx = (long long)TT * 1024;
      p.Bh = catH; p.Bl = catL;
      p.bias = bias1; p.xbias = xbias;
      p.o0 = qkvg; p.xkv = xkvF;
      gemm_k<1><<<dim3(720), 256, 0, stream>>>(p);
    }
    attn_k<<<dim3(512), 128, 0, stream>>>(qkvg, xkvF, attnH, attnL);
    { // attn @ Wo + bo + mem
      GP p = {};
      p.Ah = attnH; p.Al = attnL;
      p.Bh = woH; p.Bl = woL;
      p.bias = bo; p.rf = memF;
      p.o0 = naF; p.oh = naH; p.ol = naL;
      gemm_k<2><<<dim3(512), 256, 0, stream>>>(p);
    }
    { // relu(na @ Wm1 + bm1)
      GP p = {};
      p.Ah = naH; p.Al = naL;
      p.Bh = wm1H; p.Bl = wm1L;
      p.bias = bm1;
      p.oh = hidH; p.ol = hidL;
      gemm_k<3><<<dim3(512), 256, 0, stream>>>(p);
    }
    { // hid @ Wm2 + gates -> mem
      GP p = {};
      p.Ah = hidH; p.Al = hidL;
      p.Bh = wm2H; p.Bl = wm2L;
      p.bias = bm2; p.rf = naF;
      p.g1 = xkvF; p.g2 = qkvg; p.memf = memF;
      p.oh = memH; p.ol = memL;
      p.o2h = tmemH; p.o2l = tmemL;
      gemm_k<4><<<dim3(512), 256, 0, stream>>>(p);
    }
  }

  hipMemcpyAsync(d_out, memF, (size_t)512 * 1024 * 4, hipMemcpyDeviceToDevice, stream);
}